// Round 4
// baseline (1356.633 us; speedup 1.0000x reference)
//
#include <hip/hip_runtime.h>

// CrossShareUnit: B=8192, L=1, DL=DM=1024, K=8
// out order: [l_out | m_out | l_attn | m_attn], each 8192*1024 fp32.

#define NB 8192
#define DD 1024

typedef __bf16 bf16x8 __attribute__((ext_vector_type(8)));
typedef float f32x4 __attribute__((ext_vector_type(4)));

__device__ __forceinline__ unsigned short f2bf(float f) {
  unsigned u = __float_as_uint(f);
  u += 0x7FFFu + ((u >> 16) & 1u);   // RNE to bf16
  return (unsigned short)(u >> 16);
}
__device__ __forceinline__ float bf2f(unsigned short h) {
  return __uint_as_float(((unsigned)h) << 16);
}

// ---- split fp32 -> bf16 hi + bf16 lo (row-major [NB x DD]) ----
__global__ __launch_bounds__(256) void split_cast_k(
    const float* __restrict__ in, unsigned short* __restrict__ hi,
    unsigned short* __restrict__ lo, int n4) {
  int i = blockIdx.x * 256 + threadIdx.x;
  if (i >= n4) return;
  float4 v = reinterpret_cast<const float4*>(in)[i];
  float vv[4] = {v.x, v.y, v.z, v.w};
  unsigned short hh[4], ll[4];
#pragma unroll
  for (int c = 0; c < 4; ++c) {
    hh[c] = f2bf(vv[c]);
    ll[c] = f2bf(vv[c] - bf2f(hh[c]));
  }
  reinterpret_cast<ushort4*>(hi)[i] = make_ushort4(hh[0], hh[1], hh[2], hh[3]);
  reinterpret_cast<ushort4*>(lo)[i] = make_ushort4(ll[0], ll[1], ll[2], ll[3]);
}

// ---- transpose+split G [1024 x 8192] -> Bt rows 0..8191 ([col][d]) ----
__global__ __launch_bounds__(256) void transpose_split_k(
    const float* __restrict__ G, unsigned short* __restrict__ bhi,
    unsigned short* __restrict__ blo) {
  __shared__ float t[32][33];
  int c0 = blockIdx.x * 32;
  int d0 = blockIdx.y * 32;
  int tx = threadIdx.x & 31;
  int tg = threadIdx.x >> 5;
#pragma unroll
  for (int s = 0; s < 4; ++s) {
    int dr = tg * 4 + s;
    t[dr][tx] = G[(size_t)(d0 + dr) * 8192 + c0 + tx];
  }
  __syncthreads();
#pragma unroll
  for (int s = 0; s < 4; ++s) {
    int cr = tg * 4 + s;
    float v = t[tx][cr];
    size_t o = (size_t)(c0 + cr) * 1024 + d0 + tx;
    unsigned short h = f2bf(v);
    bhi[o] = h;
    blo[o] = f2bf(v - bf2f(h));
  }
}

// ---- Wc^T = (W2·W1)^T into Bt rows 8192..9215, plus bc = W2·b1 + b2 ----
__global__ __launch_bounds__(256) void wct_k(
    const float* __restrict__ w1, const float* __restrict__ b1,
    const float* __restrict__ w2, const float* __restrict__ b2, int J,
    unsigned short* __restrict__ bhi, unsigned short* __restrict__ blo,
    float* __restrict__ bc) {
  __shared__ float w2row[256];
  int n = blockIdx.x;
  int tid = threadIdx.x;
  if (tid < J) w2row[tid] = w2[n * J + tid];
  __syncthreads();
#pragma unroll
  for (int s = 0; s < 4; ++s) {
    int i = tid + s * 256;
    float acc = 0.f;
    for (int j = 0; j < J; ++j) acc = fmaf(w2row[j], w1[j * 1024 + i], acc);
    size_t o = (size_t)(8192 + n) * 1024 + i;
    unsigned short h = f2bf(acc);
    bhi[o] = h;
    blo[o] = f2bf(acc - bf2f(h));
  }
  if (tid == 0) {
    float acc = 0.f;
    for (int j = 0; j < J; ++j) acc = fmaf(w2row[j], b1[j], acc);
    bc[n] = acc + b2[n];
  }
}

// ============================================================================
// 256x256 single-barrier-per-tile GEMM, K-split x3.
// C[b,n] = sum_k Aseg[b,k]*Bseg[n,k], K=3072 as 3 segs: (Ahi,Bhi),(Alo,Bhi),
// (Ahi,Blo).  Every block does EXACTLY 16 K-tiles of one segment (x-blocks:
// 32by x 32bx x 3seg = 3072; gvec blocks: hi*hi only, 128) -> 3200 uniform
// blocks = 12.5 waves of 256 CUs (fine-grain tail).
// Per tile: stage(t+1, all 4 quarters) -> interleaved {ds_read quadrant
// operands / 16-MFMA quadrant} x4 with NO intra-tile barriers (waves de-phase:
// one wave's ds_reads overlap another's MFMAs; setprio arbitrates) ->
// vmcnt(0) [full-tile issue-to-wait cover] -> s_barrier.
// Hazards: tile-boundary barrier guarantees (a) all waves' reads of buffer
// cb done before tile t+1 stages overwrite it, (b) all waves' stages to cb^1
// drained (own vmcnt(0)) and visible before tile t+1 reads it.
// Swizzle (rule #21): LDS linear (gload_lds), global SOURCE slot ^= row&7,
// ds_read slot ^= row&7.  LDS = 128 KB (2x2x16KB A | same B), no sink.
// ============================================================================
#define SBAR() do { asm volatile("" ::: "memory"); __builtin_amdgcn_s_barrier(); asm volatile("" ::: "memory"); } while (0)
#define WAITV0() asm volatile("s_waitcnt vmcnt(0)" ::: "memory")

#define GLOAD(SRC, DST)                                              \
  __builtin_amdgcn_global_load_lds(                                  \
      (const __attribute__((address_space(1))) void*)(SRC),          \
      (__attribute__((address_space(3))) void*)(lds + (DST)), 16, 0, 0)

__global__ __launch_bounds__(512, 2) void gemm_k(
    const unsigned short* __restrict__ Ahi_, const unsigned short* __restrict__ Alo_,
    const unsigned short* __restrict__ Bhi_, const unsigned short* __restrict__ Blo_,
    const float* __restrict__ hb, float* __restrict__ gvec, float* __restrict__ x) {
  __shared__ __align__(16) char lds[131072];
  const char* Ah = (const char*)Ahi_;
  const char* Al = (const char*)Alo_;
  const char* Bh = (const char*)Bhi_;
  const char* Bl = (const char*)Blo_;

  const int tid = threadIdx.x;
  const int lane = tid & 63;
  const int wid = tid >> 6;
  const int wm = wid >> 2, wn = wid & 3;   // wave covers 64x32 of each quadrant

  // XCD-aware decode: each XCD owns a 4-row M-band; 3200 = 8 * 400.
  // j<384: x-blocks  seg=j>>7, bx=(j&127)>>2, by=xcd*4+(j&3)
  // j>=384: gvec     bx=(j-384)>>2, by=xcd*4+(j&3), seg=0 (hi*hi only)
  const int bid = blockIdx.x;
  const int xcd = bid & 7;
  const int j = bid >> 3;
  const bool isg = (j >= 384);
  const int r = isg ? (j - 384) : (j & 127);
  const int seg = isg ? 0 : (j >> 7);
  const int by = xcd * 4 + (r & 3);
  const int bx = r >> 2;
  const int m0 = by * 256;
  const int n0 = isg ? (8192 + bx * 256) : (bx * 256);

  const char* Ab = (seg == 1) ? Al : Ah;
  const char* Bb = (seg == 2) ? Bl : Bh;

  const int rowl = tid >> 3;                               // staged row 0..63
  const int colsw = ((tid & 7) ^ ((tid >> 3) & 7)) << 4;   // pre-swizzled src slot
  const int s0 = ((lane >> 4) ^ (lane & 7)) << 4;          // ds_read slot ks=0
  const int s1 = s0 ^ 64;                                  // ks=1

  f32x4 acc[4][4][2] = {};   // [quadrant 0:(00) 1:(01) 2:(11) 3:(10)][f][g]

  // q: 0=A rows 0..127, 1=A rows 128..255, 2=B rows 0..127, 3=B rows 128..255
  auto stage = [&](int tl, int q) {
    const char* mat;
    int rowbase, dst;
    if (q < 2) {
      mat = Ab;
      rowbase = m0 + q * 128;
      dst = (tl & 1) * 32768 + q * 16384;
    } else {
      mat = Bb;
      rowbase = n0 + (q - 2) * 128;
      dst = 65536 + (tl & 1) * 32768 + (q - 2) * 16384;
    }
    const char* src = mat + (size_t)(rowbase + rowl) * 2048 + (tl << 7) + colsw;
    dst += wid * 1024;                    // wave-uniform LDS base
    GLOAD(src, dst);                      // rows 0..63 of quarter
    GLOAD(src + 64 * 2048, dst + 8192);   // rows 64..127
  };

  auto ldA = [&](bf16x8 (*d)[2], int qa, int cb) {
    const char* p = lds + cb + qa * 16384 + (wm * 64 + (lane & 15)) * 128;
#pragma unroll
    for (int f = 0; f < 4; ++f) {
      d[f][0] = *reinterpret_cast<const bf16x8*>(p + f * 2048 + s0);
      d[f][1] = *reinterpret_cast<const bf16x8*>(p + f * 2048 + s1);
    }
  };
  auto ldB = [&](bf16x8 (*d)[2], int qb, int cb) {
    const char* p = lds + 65536 + cb + qb * 16384 + (wn * 32 + (lane & 15)) * 128;
#pragma unroll
    for (int g = 0; g < 2; ++g) {
      d[g][0] = *reinterpret_cast<const bf16x8*>(p + g * 2048 + s0);
      d[g][1] = *reinterpret_cast<const bf16x8*>(p + g * 2048 + s1);
    }
  };
  auto mm = [&](f32x4 (*ac)[2], bf16x8 (*aa)[2], bf16x8 (*bb)[2]) {
#pragma unroll
    for (int f = 0; f < 4; ++f)
#pragma unroll
      for (int g = 0; g < 2; ++g) {
        ac[f][g] = __builtin_amdgcn_mfma_f32_16x16x32_bf16(aa[f][0], bb[g][0], ac[f][g], 0, 0, 0);
        ac[f][g] = __builtin_amdgcn_mfma_f32_16x16x32_bf16(aa[f][1], bb[g][1], ac[f][g], 0, 0, 0);
      }
  };

  // prologue: stage tile 0, drain, sync
  stage(0, 0); stage(0, 1); stage(0, 2); stage(0, 3);
  WAITV0();
  SBAR();

  bf16x8 af[4][2], af2[4][2], bv[2][2], bv2[2][2];
  for (int t = 0; t < 16; ++t) {
    const int cb = (t & 1) * 32768;
    if (t < 15) {  // stage next tile into cb^1 (WAR-safe: barrier crossed)
      stage(t + 1, 0); stage(t + 1, 1); stage(t + 1, 2); stage(t + 1, 3);
    }
    // quadrant ops with operand prefetch one quadrant ahead; no barriers.
    ldA(af, 0, cb);
    ldB(bv, 0, cb);
    ldB(bv2, 1, cb);
    __builtin_amdgcn_s_setprio(1);
    mm(acc[0], af, bv);            // (0,0)
    __builtin_amdgcn_s_setprio(0);
    ldA(af2, 1, cb);
    __builtin_amdgcn_s_setprio(1);
    mm(acc[1], af, bv2);           // (0,1)
    mm(acc[2], af2, bv2);          // (1,1)
    mm(acc[3], af2, bv);           // (1,0)
    __builtin_amdgcn_s_setprio(0);
    WAITV0();                      // own stages (full-tile cover) drained
    SBAR();                        // all waves: reads done + stages visible
  }

  // ---- epilogue (registers only) ----
  const int coll = lane & 15;
  const int rg = (lane >> 4) * 4;
  if (isg) {
#pragma unroll
    for (int q = 0; q < 4; ++q) {
      const int qm = (q >= 2);
      const int qn = (q == 1 || q == 2);
#pragma unroll
      for (int f = 0; f < 4; ++f)
#pragma unroll
        for (int rr = 0; rr < 4; ++rr) {
          const int row = m0 + qm * 128 + wm * 64 + f * 16 + rg + rr;
#pragma unroll
          for (int g = 0; g < 2; ++g) {
            const int gcol = (n0 - 8192) + qn * 128 + wn * 32 + g * 16 + coll;
            gvec[(size_t)row * 1024 + gcol] = acc[q][f][g][rr];
          }
        }
    }
  } else {
    const int kidx = n0 >> 10;
    const int ebase = (n0 & 1023) + wn * 32 + coll;
#pragma unroll
    for (int qm = 0; qm < 2; ++qm) {
      f32x4 (*acA)[2] = acc[qm ? 3 : 0];  // qn=0
      f32x4 (*acB)[2] = acc[qm ? 2 : 1];  // qn=1
#pragma unroll
      for (int f = 0; f < 4; ++f)
#pragma unroll
        for (int rr = 0; rr < 4; ++rr) {
          const int row = m0 + qm * 128 + wm * 64 + f * 16 + rg + rr;
          const float* hr = hb + (size_t)row * 1024 + ebase;
          float tmp = acA[f][0][rr] * hr[0] + acA[f][1][rr] * hr[16] +
                      acB[f][0][rr] * hr[128] + acB[f][1][rr] * hr[144];
#pragma unroll
          for (int s = 1; s < 16; s <<= 1) tmp += __shfl_xor(tmp, s);
          if (coll == 0) atomicAdd(&x[row * 8 + kidx], tmp);
        }
    }
  }
}

// ---- per-batch: S = sum tanh(x), vec = S*(gvec+bc), softmax, out/attn ----
__global__ __launch_bounds__(256) void finalize_k(
    const float* __restrict__ xk, const float* __restrict__ gvec,
    const float* __restrict__ bc, const float* __restrict__ ha,
    float* __restrict__ out, float* __restrict__ attn) {
  int b = blockIdx.x;
  int tid = threadIdx.x;
  float S = 0.f;
#pragma unroll
  for (int k = 0; k < 8; ++k) S += tanhf(xk[b * 8 + k]);
  float v[4];
  float mx = -3.4e38f;
#pragma unroll
  for (int s = 0; s < 4; ++s) {
    int d = tid + s * 256;
    v[s] = S * (gvec[(size_t)b * 1024 + d] + bc[d]);
    mx = fmaxf(mx, v[s]);
  }
  __shared__ float red[8];
#pragma unroll
  for (int off = 32; off >= 1; off >>= 1) mx = fmaxf(mx, __shfl_xor(mx, off));
  int lane = tid & 63, w = tid >> 6;
  if (lane == 0) red[w] = mx;
  __syncthreads();
  float m = fmaxf(fmaxf(red[0], red[1]), fmaxf(red[2], red[3]));
  float e[4], sum = 0.f;
#pragma unroll
  for (int s = 0; s < 4; ++s) { e[s] = __expf(v[s] - m); sum += e[s]; }
#pragma unroll
  for (int off = 32; off >= 1; off >>= 1) sum += __shfl_xor(sum, off);
  if (lane == 0) red[4 + w] = sum;
  __syncthreads();
  float inv = 1.f / (red[4] + red[5] + red[6] + red[7]);
#pragma unroll
  for (int s = 0; s < 4; ++s) {
    int d = tid + s * 256;
    float a = e[s] * inv;
    attn[(size_t)b * 1024 + d] = a;
    float h = ha[(size_t)b * 1024 + d];
    out[(size_t)b * 1024 + d] = fmaf(a, h, h);
  }
}

extern "C" void kernel_launch(void* const* d_in, const int* in_sizes, int n_in,
                              void* d_out, int out_size, void* d_ws, size_t ws_size,
                              hipStream_t stream) {
  const float* l_hidden = (const float*)d_in[0];
  const float* m_hidden = (const float*)d_in[1];
  const float* G_l_m = (const float*)d_in[2];
  const float* G_m_l = (const float*)d_in[3];
  const float* l_fc1_w = (const float*)d_in[4];
  const float* l_fc1_b = (const float*)d_in[5];
  const float* l_fc2_w = (const float*)d_in[6];
  const float* l_fc2_b = (const float*)d_in[7];
  const float* m_fc1_w = (const float*)d_in[8];
  const float* m_fc1_b = (const float*)d_in[9];
  const float* m_fc2_w = (const float*)d_in[10];
  const float* m_fc2_b = (const float*)d_in[11];
  float* out = (float*)d_out;

  char* ws = (char*)d_ws;
  unsigned short* Ahi = (unsigned short*)(ws);                    // 16 MB
  unsigned short* Alo = (unsigned short*)(ws + 16777216);         // 16 MB
  unsigned short* Bhi = (unsigned short*)(ws + 33554432);         // 18 MB (9216x1024)
  unsigned short* Blo = (unsigned short*)(ws + 52428800);         // 18 MB
  float* gvec = (float*)(ws + 71303168);                          // 32 MB
  float* x = (float*)(ws + 104857600);                            // 512 KB (2 dirs)
  float* bc = (float*)(ws + 105381888);                           // 4 KB

  hipMemsetAsync(x, 0, 2 * NB * 8 * sizeof(float), stream);

  const size_t BD = (size_t)NB * DD;
  dim3 gemmGrid(3200);

  // direction l
  split_cast_k<<<(int)(BD / 4 / 256), 256, 0, stream>>>(l_hidden, Ahi, Alo, (int)(BD / 4));
  transpose_split_k<<<dim3(256, 32), 256, 0, stream>>>(G_l_m, Bhi, Blo);
  wct_k<<<1024, 256, 0, stream>>>(l_fc1_w, l_fc1_b, l_fc2_w, l_fc2_b, 256, Bhi, Blo, bc);
  gemm_k<<<gemmGrid, 512, 0, stream>>>(Ahi, Alo, Bhi, Blo, m_hidden, gvec, x);
  finalize_k<<<NB, 256, 0, stream>>>(x, gvec, bc, l_hidden, out, out + 2 * BD);

  // direction m
  split_cast_k<<<(int)(BD / 4 / 256), 256, 0, stream>>>(m_hidden, Ahi, Alo, (int)(BD / 4));
  transpose_split_k<<<dim3(256, 32), 256, 0, stream>>>(G_m_l, Bhi, Blo);
  wct_k<<<1024, 256, 0, stream>>>(m_fc1_w, m_fc1_b, m_fc2_w, m_fc2_b, 128, Bhi, Blo, bc);
  gemm_k<<<gemmGrid, 512, 0, stream>>>(Ahi, Alo, Bhi, Blo, l_hidden, gvec, x + NB * 8);
  finalize_k<<<NB, 256, 0, stream>>>(x + NB * 8, gvec, bc, m_hidden, out + BD, out + 3 * BD);
}

// Round 5
// 1060.417 us; speedup vs baseline: 1.2793x; 1.2793x over previous
//
#include <hip/hip_runtime.h>

// CrossShareUnit: B=8192, L=1, DL=DM=1024, K=8
// out order: [l_out | m_out | l_attn | m_attn], each 8192*1024 fp32.

#define NB 8192
#define DD 1024

typedef __bf16 bf16x8 __attribute__((ext_vector_type(8)));
typedef float f32x4 __attribute__((ext_vector_type(4)));

__device__ __forceinline__ unsigned short f2bf(float f) {
  unsigned u = __float_as_uint(f);
  u += 0x7FFFu + ((u >> 16) & 1u);   // RNE to bf16
  return (unsigned short)(u >> 16);
}
__device__ __forceinline__ float bf2f(unsigned short h) {
  return __uint_as_float(((unsigned)h) << 16);
}

// ---- split fp32 -> bf16 hi + bf16 lo (row-major [NB x DD]) ----
__global__ __launch_bounds__(256) void split_cast_k(
    const float* __restrict__ in, unsigned short* __restrict__ hi,
    unsigned short* __restrict__ lo, int n4) {
  int i = blockIdx.x * 256 + threadIdx.x;
  if (i >= n4) return;
  float4 v = reinterpret_cast<const float4*>(in)[i];
  float vv[4] = {v.x, v.y, v.z, v.w};
  unsigned short hh[4], ll[4];
#pragma unroll
  for (int c = 0; c < 4; ++c) {
    hh[c] = f2bf(vv[c]);
    ll[c] = f2bf(vv[c] - bf2f(hh[c]));
  }
  reinterpret_cast<ushort4*>(hi)[i] = make_ushort4(hh[0], hh[1], hh[2], hh[3]);
  reinterpret_cast<ushort4*>(lo)[i] = make_ushort4(ll[0], ll[1], ll[2], ll[3]);
}

// ---- transpose+split G [1024 x 8192] -> Bt rows 0..8191 ([col][d]) ----
__global__ __launch_bounds__(256) void transpose_split_k(
    const float* __restrict__ G, unsigned short* __restrict__ bhi,
    unsigned short* __restrict__ blo) {
  __shared__ float t[32][33];
  int c0 = blockIdx.x * 32;
  int d0 = blockIdx.y * 32;
  int tx = threadIdx.x & 31;
  int tg = threadIdx.x >> 5;
#pragma unroll
  for (int s = 0; s < 4; ++s) {
    int dr = tg * 4 + s;
    t[dr][tx] = G[(size_t)(d0 + dr) * 8192 + c0 + tx];
  }
  __syncthreads();
#pragma unroll
  for (int s = 0; s < 4; ++s) {
    int cr = tg * 4 + s;
    float v = t[tx][cr];
    size_t o = (size_t)(c0 + cr) * 1024 + d0 + tx;
    unsigned short h = f2bf(v);
    bhi[o] = h;
    blo[o] = f2bf(v - bf2f(h));
  }
}

// ---- Wc^T = (W2·W1)^T into Bt rows 8192..9215, plus bc = W2·b1 + b2 ----
__global__ __launch_bounds__(256) void wct_k(
    const float* __restrict__ w1, const float* __restrict__ b1,
    const float* __restrict__ w2, const float* __restrict__ b2, int J,
    unsigned short* __restrict__ bhi, unsigned short* __restrict__ blo,
    float* __restrict__ bc) {
  __shared__ float w2row[256];
  int n = blockIdx.x;
  int tid = threadIdx.x;
  if (tid < J) w2row[tid] = w2[n * J + tid];
  __syncthreads();
#pragma unroll
  for (int s = 0; s < 4; ++s) {
    int i = tid + s * 256;
    float acc = 0.f;
    for (int j = 0; j < J; ++j) acc = fmaf(w2row[j], w1[j * 1024 + i], acc);
    size_t o = (size_t)(8192 + n) * 1024 + i;
    unsigned short h = f2bf(acc);
    bhi[o] = h;
    blo[o] = f2bf(acc - bf2f(h));
  }
  if (tid == 0) {
    float acc = 0.f;
    for (int j = 0; j < J; ++j) acc = fmaf(w2row[j], b1[j], acc);
    bc[n] = acc + b2[n];
  }
}

// ============================================================================
// 256x256 quadrant-phased GEMM, 4 barriers/tile, counted lgkm operand
// prefetch + 2 counted vmcnt/tile.  C[b,n] = sum_k Aseg[b,k]*Bseg[n,k],
// K=3072 as 3 segs: (Ahi,Bhi),(Alo,Bhi),(Ahi,Blo).  48 tiles per x-block.
// Phase p computes one C-quadrant; reads for phase p+1 issue BEFORE phase
// p's barrier so compiler emits counted lgkmcnt and the LDS queue drains
// under the MFMA cluster (the m201 overlap mechanism).
// Stage order (tile t stages tile t+1): ph0->A0, ph1->B0, ph2->B1, ph3->A1.
// Wait ledger (outstanding gloads per wave, 2 per stage):
//   ph0: out = A1(t)+A0(t+1)=4 -> WAITV2 drains A1(t)  [read at ph1]
//   ph3: out = A0,B0,B1,A1(t+1)=8 -> WAITV2 drains A0,B0,B1 [read at ph0]
// Cover >= 1 phase for every load; never drains below 2 except last tile.
// Swizzle (rule #21): LDS linear (gload_lds), global SOURCE slot ^= row&7,
// ds_read slot ^= row&7.  LDS = 128 KB.
// ============================================================================
#define SBAR() do { asm volatile("" ::: "memory"); __builtin_amdgcn_s_barrier(); asm volatile("" ::: "memory"); } while (0)
#define WAITV0() asm volatile("s_waitcnt vmcnt(0)" ::: "memory")
#define WAITV2() asm volatile("s_waitcnt vmcnt(2)" ::: "memory")

#define GLOAD(SRC, DST)                                              \
  __builtin_amdgcn_global_load_lds(                                  \
      (const __attribute__((address_space(1))) void*)(SRC),          \
      (__attribute__((address_space(3))) void*)(lds + (DST)), 16, 0, 0)

__global__ __launch_bounds__(512, 2) void gemm_k(
    const unsigned short* __restrict__ Ahi_, const unsigned short* __restrict__ Alo_,
    const unsigned short* __restrict__ Bhi_, const unsigned short* __restrict__ Blo_,
    const float* __restrict__ hb, float* __restrict__ gvec, float* __restrict__ x) {
  __shared__ __align__(16) char lds[131072];
  const char* Ah = (const char*)Ahi_;
  const char* Al = (const char*)Alo_;
  const char* Bh = (const char*)Bhi_;
  const char* Bl = (const char*)Blo_;

  const int tid = threadIdx.x;
  const int lane = tid & 63;
  const int wid = tid >> 6;
  const int wm = wid >> 2, wn = wid & 3;   // wave: 64 A-rows x 32 B-cols per quadrant

  // XCD-aware: each XCD owns a 4-row M-band; 4 neighbors share each B panel.
  const int bid = blockIdx.x;
  const int xcd = bid & 7;
  const int j = bid >> 3;                  // 0..143
  const int by = xcd * 4 + (j & 3);        // 0..31
  const int bx = j >> 2;                   // 0..35
  const int m0 = by * 256;
  const int n0 = bx * 256;
  const bool isg = (n0 >= 8192);
  const int nt = isg ? 16 : 48;            // gvec tiles: hi*hi only

  const int rowl = tid >> 3;                               // staged row 0..63
  const int colsw = ((tid & 7) ^ ((tid >> 3) & 7)) << 4;   // pre-swizzled src slot
  const int s0 = ((lane >> 4) ^ (lane & 7)) << 4;          // ds_read slot ks=0
  const int s1 = s0 ^ 64;                                  // ks=1

  f32x4 acc[4][4][2] = {};   // [quadrant 0:(00) 1:(01) 2:(11) 3:(10)][f][g]

  // q: 0=A rows 0..127, 1=A rows 128..255, 2=B rows 0..127, 3=B rows 128..255
  auto stage = [&](int tl, int q) {
    if (tl >= nt) return;
    const int seg = tl >> 4;
    const char* mat;
    int rowbase, dst;
    if (q < 2) {
      mat = (seg == 1) ? Al : Ah;
      rowbase = m0 + q * 128;
      dst = (tl & 1) * 32768 + q * 16384;
    } else {
      mat = (seg == 2) ? Bl : Bh;
      rowbase = n0 + (q - 2) * 128;
      dst = 65536 + (tl & 1) * 32768 + (q - 2) * 16384;
    }
    const char* src = mat + (size_t)(rowbase + rowl) * 2048 + ((tl & 15) << 7) + colsw;
    dst += wid * 1024;                    // wave-uniform LDS base
    GLOAD(src, dst);                      // rows 0..63 of quarter
    GLOAD(src + 64 * 2048, dst + 8192);   // rows 64..127
  };

  auto ldA = [&](bf16x8 (*d)[2], int qa, int cb) {
    const char* p = lds + cb + qa * 16384 + (wm * 64 + (lane & 15)) * 128;
#pragma unroll
    for (int f = 0; f < 4; ++f) {
      d[f][0] = *reinterpret_cast<const bf16x8*>(p + f * 2048 + s0);
      d[f][1] = *reinterpret_cast<const bf16x8*>(p + f * 2048 + s1);
    }
  };
  auto ldB = [&](bf16x8 (*d)[2], int qb, int cb) {
    const char* p = lds + 65536 + cb + qb * 16384 + (wn * 32 + (lane & 15)) * 128;
#pragma unroll
    for (int g = 0; g < 2; ++g) {
      d[g][0] = *reinterpret_cast<const bf16x8*>(p + g * 2048 + s0);
      d[g][1] = *reinterpret_cast<const bf16x8*>(p + g * 2048 + s1);
    }
  };
  auto mm = [&](f32x4 (*ac)[2], bf16x8 (*aa)[2], bf16x8 (*bb)[2]) {
#pragma unroll
    for (int f = 0; f < 4; ++f)
#pragma unroll
      for (int g = 0; g < 2; ++g) {
        ac[f][g] = __builtin_amdgcn_mfma_f32_16x16x32_bf16(aa[f][0], bb[g][0], ac[f][g], 0, 0, 0);
        ac[f][g] = __builtin_amdgcn_mfma_f32_16x16x32_bf16(aa[f][1], bb[g][1], ac[f][g], 0, 0, 0);
      }
  };

  // prologue: stage tile0 (A0,B0,B1 drained; A1 left in flight) -> steady state
  stage(0, 0); stage(0, 2); stage(0, 3); stage(0, 1);
  WAITV2();
  SBAR();

  bf16x8 af[4][2], af2[4][2], bv[2][2], bv2[2][2];
  for (int t = 0; t < nt; ++t) {
    const int cb = (t & 1) * 32768;
    // ph0: quadrant (0,0); reads for ph0+ph1's B, prefetch bv2
    ldA(af, 0, cb);
    ldB(bv, 0, cb);
    ldB(bv2, 1, cb);                 // stays in flight past mm0 (counted lgkm)
    stage(t + 1, 0);
    __builtin_amdgcn_s_setprio(1);
    mm(acc[0], af, bv);
    __builtin_amdgcn_s_setprio(0);
    if (t + 1 < nt) { WAITV2(); } else { WAITV0(); }   // drain A1(t)
    SBAR();
    // ph1: quadrant (0,1); prefetch af2 under mm1
    ldA(af2, 1, cb);
    stage(t + 1, 2);
    __builtin_amdgcn_s_setprio(1);
    mm(acc[1], af, bv2);
    __builtin_amdgcn_s_setprio(0);
    SBAR();
    // ph2: quadrant (1,1); no new reads
    stage(t + 1, 3);
    __builtin_amdgcn_s_setprio(1);
    mm(acc[2], af2, bv2);
    __builtin_amdgcn_s_setprio(0);
    SBAR();
    // ph3: quadrant (1,0); bv still live (no re-read)
    stage(t + 1, 1);
    __builtin_amdgcn_s_setprio(1);
    mm(acc[3], af2, bv);
    __builtin_amdgcn_s_setprio(0);
    WAITV2();                        // drain A0,B0,B1 of t+1
    SBAR();
  }

  // ---- epilogue (registers only) ----
  const int coll = lane & 15;
  const int rg = (lane >> 4) * 4;
  if (isg) {
#pragma unroll
    for (int q = 0; q < 4; ++q) {
      const int qm = (q >= 2);
      const int qn = (q == 1 || q == 2);
#pragma unroll
      for (int f = 0; f < 4; ++f)
#pragma unroll
        for (int rr = 0; rr < 4; ++rr) {
          const int row = m0 + qm * 128 + wm * 64 + f * 16 + rg + rr;
#pragma unroll
          for (int g = 0; g < 2; ++g) {
            const int gcol = (n0 - 8192) + qn * 128 + wn * 32 + g * 16 + coll;
            gvec[(size_t)row * 1024 + gcol] = acc[q][f][g][rr];
          }
        }
    }
  } else {
    const int kidx = n0 >> 10;
    const int ebase = (n0 & 1023) + wn * 32 + coll;
#pragma unroll
    for (int qm = 0; qm < 2; ++qm) {
      f32x4 (*acA)[2] = acc[qm ? 3 : 0];  // qn=0
      f32x4 (*acB)[2] = acc[qm ? 2 : 1];  // qn=1
#pragma unroll
      for (int f = 0; f < 4; ++f)
#pragma unroll
        for (int rr = 0; rr < 4; ++rr) {
          const int row = m0 + qm * 128 + wm * 64 + f * 16 + rg + rr;
          const float* hr = hb + (size_t)row * 1024 + ebase;
          float tmp = acA[f][0][rr] * hr[0] + acA[f][1][rr] * hr[16] +
                      acB[f][0][rr] * hr[128] + acB[f][1][rr] * hr[144];
#pragma unroll
          for (int s = 1; s < 16; s <<= 1) tmp += __shfl_xor(tmp, s);
          if (coll == 0) atomicAdd(&x[row * 8 + kidx], tmp);
        }
    }
  }
}

// ---- per-batch: S = sum tanh(x), vec = S*(gvec+bc), softmax, out/attn ----
__global__ __launch_bounds__(256) void finalize_k(
    const float* __restrict__ xk, const float* __restrict__ gvec,
    const float* __restrict__ bc, const float* __restrict__ ha,
    float* __restrict__ out, float* __restrict__ attn) {
  int b = blockIdx.x;
  int tid = threadIdx.x;
  float S = 0.f;
#pragma unroll
  for (int k = 0; k < 8; ++k) S += tanhf(xk[b * 8 + k]);
  float v[4];
  float mx = -3.4e38f;
#pragma unroll
  for (int s = 0; s < 4; ++s) {
    int d = tid + s * 256;
    v[s] = S * (gvec[(size_t)b * 1024 + d] + bc[d]);
    mx = fmaxf(mx, v[s]);
  }
  __shared__ float red[8];
#pragma unroll
  for (int off = 32; off >= 1; off >>= 1) mx = fmaxf(mx, __shfl_xor(mx, off));
  int lane = tid & 63, w = tid >> 6;
  if (lane == 0) red[w] = mx;
  __syncthreads();
  float m = fmaxf(fmaxf(red[0], red[1]), fmaxf(red[2], red[3]));
  float e[4], sum = 0.f;
#pragma unroll
  for (int s = 0; s < 4; ++s) { e[s] = __expf(v[s] - m); sum += e[s]; }
#pragma unroll
  for (int off = 32; off >= 1; off >>= 1) sum += __shfl_xor(sum, off);
  if (lane == 0) red[4 + w] = sum;
  __syncthreads();
  float inv = 1.f / (red[4] + red[5] + red[6] + red[7]);
#pragma unroll
  for (int s = 0; s < 4; ++s) {
    int d = tid + s * 256;
    float a = e[s] * inv;
    attn[(size_t)b * 1024 + d] = a;
    float h = ha[(size_t)b * 1024 + d];
    out[(size_t)b * 1024 + d] = fmaf(a, h, h);
  }
}

extern "C" void kernel_launch(void* const* d_in, const int* in_sizes, int n_in,
                              void* d_out, int out_size, void* d_ws, size_t ws_size,
                              hipStream_t stream) {
  const float* l_hidden = (const float*)d_in[0];
  const float* m_hidden = (const float*)d_in[1];
  const float* G_l_m = (const float*)d_in[2];
  const float* G_m_l = (const float*)d_in[3];
  const float* l_fc1_w = (const float*)d_in[4];
  const float* l_fc1_b = (const float*)d_in[5];
  const float* l_fc2_w = (const float*)d_in[6];
  const float* l_fc2_b = (const float*)d_in[7];
  const float* m_fc1_w = (const float*)d_in[8];
  const float* m_fc1_b = (const float*)d_in[9];
  const float* m_fc2_w = (const float*)d_in[10];
  const float* m_fc2_b = (const float*)d_in[11];
  float* out = (float*)d_out;

  char* ws = (char*)d_ws;
  unsigned short* Ahi = (unsigned short*)(ws);                    // 16 MB
  unsigned short* Alo = (unsigned short*)(ws + 16777216);         // 16 MB
  unsigned short* Bhi = (unsigned short*)(ws + 33554432);         // 18 MB (9216x1024)
  unsigned short* Blo = (unsigned short*)(ws + 52428800);         // 18 MB
  float* gvec = (float*)(ws + 71303168);                          // 32 MB
  float* x = (float*)(ws + 104857600);                            // 512 KB (2 dirs)
  float* bc = (float*)(ws + 105381888);                           // 4 KB

  hipMemsetAsync(x, 0, 2 * NB * 8 * sizeof(float), stream);

  const size_t BD = (size_t)NB * DD;
  dim3 gemmGrid(1152);

  // direction l
  split_cast_k<<<(int)(BD / 4 / 256), 256, 0, stream>>>(l_hidden, Ahi, Alo, (int)(BD / 4));
  transpose_split_k<<<dim3(256, 32), 256, 0, stream>>>(G_l_m, Bhi, Blo);
  wct_k<<<1024, 256, 0, stream>>>(l_fc1_w, l_fc1_b, l_fc2_w, l_fc2_b, 256, Bhi, Blo, bc);
  gemm_k<<<gemmGrid, 512, 0, stream>>>(Ahi, Alo, Bhi, Blo, m_hidden, gvec, x);
  finalize_k<<<NB, 256, 0, stream>>>(x, gvec, bc, l_hidden, out, out + 2 * BD);

  // direction m
  split_cast_k<<<(int)(BD / 4 / 256), 256, 0, stream>>>(m_hidden, Ahi, Alo, (int)(BD / 4));
  transpose_split_k<<<dim3(256, 32), 256, 0, stream>>>(G_m_l, Bhi, Blo);
  wct_k<<<1024, 256, 0, stream>>>(m_fc1_w, m_fc1_b, m_fc2_w, m_fc2_b, 128, Bhi, Blo, bc);
  gemm_k<<<gemmGrid, 512, 0, stream>>>(Ahi, Alo, Bhi, Blo, l_hidden, gvec, x + NB * 8);
  finalize_k<<<NB, 256, 0, stream>>>(x + NB * 8, gvec, bc, m_hidden, out + BD, out + 3 * BD);
}